// Round 3
// baseline (302.542 us; speedup 1.0000x reference)
//
#include <hip/hip_runtime.h>
#include <math.h>

#define HW 65536
#define BN 16

// ws layout (floats):
//   ws[0] : mask-loss sum (global over B*HW)
//   ws[1] : skin-loss sum (global over B*HW)
//   per-b block of 9 at ws[2 + b*9]:
//     +0..2 : nocs   msum, cnt, dsum
//     +3..5 : locmap msum, cnt, dsum
//     +6..8 : rotmap msum, cnt, dsum
//   per-(b,j) block of 7 at ws[38 + (b*16+j)*7]:
//     +0    : S      = sum sig(score_j)*m
//     +1..3 : Nloc_c = sum sig(loc_c)*sig(score_j)*m^2
//     +4..6 : Nrot_c
// total = 38 + 64*7 = 486 floats

__device__ __forceinline__ float fsig(float x) {
    return __builtin_amdgcn_rcpf(1.0f + __expf(-x));
}

__device__ __forceinline__ float wred(float v) {
#pragma unroll
    for (int off = 32; off; off >>= 1) v += __shfl_xor(v, off, 64);
    return v;
}

// One fused kernel: every input byte read exactly once.
// 112 per-(b,j) accumulators live in registers; all wave-reduction trees
// run ONCE per block after the channel walk (round-1 ran them per-pixel
// interleaved with loads -> latency disaster; round-2 split kernels ->
// 115 MB re-read + VGPR=32 load starvation).
__global__ __launch_bounds__(256) void mvpm_fused(const float* __restrict__ outp,
                                                  const float* __restrict__ tarp,
                                                  float* __restrict__ ws) {
    const int b = blockIdx.y;
    const int p = blockIdx.x * 256 + threadIdx.x;
    const float* ob = outp + (size_t)b * 134 * HW + p;
    const float* tb = tarp + (size_t)b * 101 * HW + p;
    const int lane = threadIdx.x & 63;
    const int wv = threadIdx.x >> 6;

    __shared__ float red[123][4];

    const float m = tb[3 * HW];
    const float mm = m * m;
    const bool sel = m > 0.7f;

    // ---- mask BCE ----
    const float ml = ob[3 * HW];
    const float bce = m * fminf(ml, 0.0f) + (1.0f - m) * fminf(-ml, 0.0f)
                      - __logf(1.0f + __expf(-fabsf(ml)));

    // ---- nocs L2 ----
    float d0 = ob[0 * HW] - tb[0 * HW];
    float d1 = ob[1 * HW] - tb[1 * HW];
    float d2 = ob[2 * HW] - tb[2 * HW];
    const float dn = sqrtf(d0 * d0 + d1 * d1 + d2 * d2);

    // ---- skin CE, online logsumexp (no x[18] array -> saves 18 VGPRs) ----
    float rmax = -1e30f, rsum = 0.0f, xl = 0.0f;
    const int lab0 = (int)tb[100 * HW];
    const int lab = lab0 < 0 ? 0 : (lab0 > 17 ? 17 : lab0);
#pragma unroll
    for (int k = 0; k < 18; ++k) {
        float x = ob[(100 + k) * HW];
        float nm = fmaxf(rmax, x);
        rsum = rsum * __expf(rmax - nm) + __expf(x - nm);
        rmax = nm;
        xl = (lab == k) ? x : xl;
    }
    const float skin = rmax + __logf(rsum) - xl;

    // ---- stage the 11 pixel-loss trees now (frees regs for joint loop) ----
    {
        float v[11];
        v[0] = bce;
        v[1] = skin;
        v[2] = sel ? dn : 0.0f;
        v[3] = (sel && dn != 0.0f) ? 1.0f : 0.0f;
        v[4] = dn;
        // v[5..10] filled after the joint loop (need dsl/dsr) -- stage 0..4 now
#pragma unroll
        for (int off = 32; off; off >>= 1) {
#pragma unroll
            for (int i = 0; i < 5; ++i) v[i] += __shfl_xor(v[i], off, 64);
        }
        if (lane == 0) {
#pragma unroll
            for (int i = 0; i < 5; ++i) red[i][wv] = v[i];
        }
    }

    // ---- joint loop: shared loads feed BOTH masked-L2 and per-joint sums --
    float acc[112];   // j*7 + {S, NL0..2, NR0..2}
#pragma unroll
    for (int i = 0; i < 112; ++i) acc[i] = 0.0f;

    float dsl = 0.0f, dsr = 0.0f;
#pragma unroll
    for (int j = 0; j < BN; ++j) {
        const float w = fsig(ob[(118 + j) * HW]) * m;   // sig(score)*m
        acc[j * 7 + 0] = w;
        const float wm = w * m;                          // sig(score)*m^2
#pragma unroll
        for (int k = 0; k < 3; ++k) {
            const int c = 3 * j + k;
            float so = fsig(ob[(4 + c) * HW]);
            float st = fsig(tb[(4 + c) * HW]);
            float d = so - st;
            dsl += d * d;
            acc[j * 7 + 1 + k] = so * wm;

            float so2 = fsig(ob[(52 + c) * HW]);
            float st2 = fsig(tb[(52 + c) * HW]);
            float dd = so2 - st2;
            dsr += dd * dd;
            acc[j * 7 + 4 + k] = so2 * wm;
        }
    }

    // ---- remaining 6 pixel-loss trees ----
    {
        const float dnl = sqrtf(dsl);
        const float dnr = sqrtf(dsr);
        float v[6];
        v[0] = sel ? dnl : 0.0f;
        v[1] = (sel && dnl != 0.0f) ? 1.0f : 0.0f;
        v[2] = dnl;
        v[3] = sel ? dnr : 0.0f;
        v[4] = (sel && dnr != 0.0f) ? 1.0f : 0.0f;
        v[5] = dnr;
#pragma unroll
        for (int off = 32; off; off >>= 1) {
#pragma unroll
            for (int i = 0; i < 6; ++i) v[i] += __shfl_xor(v[i], off, 64);
        }
        if (lane == 0) {
#pragma unroll
            for (int i = 0; i < 6; ++i) red[5 + i][wv] = v[i];
        }
    }

    // ---- 112 joint trees, once per block ----
#pragma unroll
    for (int off = 32; off; off >>= 1) {
#pragma unroll
        for (int i = 0; i < 112; ++i) acc[i] += __shfl_xor(acc[i], off, 64);
    }
    if (lane == 0) {
#pragma unroll
        for (int i = 0; i < 112; ++i) red[11 + i][wv] = acc[i];
    }

    __syncthreads();
    if (threadIdx.x < 123) {
        float s = red[threadIdx.x][0] + red[threadIdx.x][1] +
                  red[threadIdx.x][2] + red[threadIdx.x][3];
        int g;
        if (threadIdx.x < 2)       g = threadIdx.x;
        else if (threadIdx.x < 11) g = 2 + b * 9 + (threadIdx.x - 2);
        else                       g = 38 + b * 112 + (threadIdx.x - 11);
        atomicAdd(&ws[g], s);
    }
}

// ---------------- finalize -----------------------------------------------
__global__ __launch_bounds__(64) void mvpm_fin(const float* __restrict__ ws,
                                               const float* __restrict__ tp,
                                               float* __restrict__ o) {
    const int t = threadIdx.x;      // 64 threads = (b, j)
    const int base = 38 + t * 7;

    float S = ws[base] + 1e-5f;
    float ln = 0.0f, rn = 0.0f;
#pragma unroll
    for (int c = 0; c < 3; ++c) {
        float pl = ws[base + 1 + c] / S;
        float tl = 1.0f / (1.0f + expf(-tp[t * 6 + c]));
        ln += (pl - tl) * (pl - tl);
        float pr = ws[base + 4 + c] / S;
        float tr = 1.0f / (1.0f + expf(-tp[t * 6 + 3 + c]));
        rn += (pr - tr) * (pr - tr);
    }
    ln = sqrtf(ln);
    rn = sqrtf(rn);
    float lsum = wred(ln);
    float rsum = wred(rn);

    if (t == 0) {
        float nocs = 0.0f, locm = 0.0f, rotm = 0.0f;
        for (int bb = 0; bb < 4; ++bb) {
            int ba = 2 + bb * 9;
            nocs += (ws[ba + 1] > 0.5f) ? ws[ba + 0] / ws[ba + 1] : ws[ba + 2] * (1.0f / HW);
            locm += (ws[ba + 4] > 0.5f) ? ws[ba + 3] / ws[ba + 4] : ws[ba + 5] * (1.0f / HW);
            rotm += (ws[ba + 7] > 0.5f) ? ws[ba + 6] / ws[ba + 7] : ws[ba + 8] * (1.0f / HW);
        }
        o[0] = nocs * 0.25f;                  // nocs_loss
        o[1] = -ws[0] / (4.0f * HW);          // mask_loss
        o[2] = lsum * (1.0f / 64.0f);         // loc_loss
        o[3] = locm * 0.25f;                  // loc_map_loss
        o[4] = rsum * (1.0f / 64.0f);         // rot_loss
        o[5] = rotm * 0.25f;                  // rot_map_loss
        o[6] = ws[1] / (4.0f * HW);           // skin_loss
    }
}

extern "C" void kernel_launch(void* const* d_in, const int* in_sizes, int n_in,
                              void* d_out, int out_size, void* d_ws, size_t ws_size,
                              hipStream_t stream) {
    const float* outp = (const float*)d_in[0];   // (4,134,256,256)
    const float* tarp = (const float*)d_in[1];   // (4,101,256,256)
    const float* tpos = (const float*)d_in[2];   // (4,16,6)
    float* o  = (float*)d_out;                   // 7 floats
    float* ws = (float*)d_ws;

    hipMemsetAsync(d_ws, 0, 486 * sizeof(float), stream);
    dim3 grid(HW / 256, 4);                      // 1024 blocks, 1 px/thread
    mvpm_fused<<<grid, 256, 0, stream>>>(outp, tarp, ws);
    mvpm_fin<<<1, 64, 0, stream>>>(ws, tpos, o);
}

// Round 4
// 290.904 us; speedup vs baseline: 1.0400x; 1.0400x over previous
//
#include <hip/hip_runtime.h>
#include <math.h>

#define HW 65536
#define BN 16

// ws layout (floats):
//   ws[0] : mask-loss sum,  ws[1] : skin-loss sum
//   per-b block of 9 at ws[2 + b*9]:
//     +0..2 : nocs msum,cnt,dsum  +3..5 : locmap  +6..8 : rotmap
//   per-(b,j) block of 7 at ws[38 + (b*16+j)*7]: S, Nloc0..2, Nrot0..2
// total = 38 + 64*7 = 486 floats

__device__ __forceinline__ float fsig(float x) {
    return __builtin_amdgcn_rcpf(1.0f + __expf(-x));
}
__device__ __forceinline__ float sq(float x) { return x * x; }

__device__ __forceinline__ float wred(float v) {
#pragma unroll
    for (int off = 32; off; off >>= 1) v += __shfl_xor(v, off, 64);
    return v;
}

// ---- Kernel A: pixel losses, 2 px/thread (float2), batched loads ---------
__global__ __launch_bounds__(256) void mvpm_pix2(const float* __restrict__ outp,
                                                 const float* __restrict__ tarp,
                                                 float* __restrict__ ws) {
    const int b = blockIdx.y;
    const int t = blockIdx.x * 256 + threadIdx.x;       // float2 index
    const int C2 = HW / 2;                              // channel stride (float2)
    const float2* ob = (const float2*)(outp + (size_t)b * 134 * HW) + t;
    const float2* tb = (const float2*)(tarp + (size_t)b * 101 * HW) + t;
    const int lane = threadIdx.x & 63;
    const int wv = threadIdx.x >> 6;

    // -- batch: mask, mask-logit, nocs (8 loads) --
    const float2 m2 = tb[3 * C2];
    const float2 ml = ob[3 * C2];
    const float2 a0 = ob[0], a1 = ob[C2], a2 = ob[2 * C2];
    const float2 b0 = tb[0], b1 = tb[C2], b2 = tb[2 * C2];

    const float bce =
        (m2.x * fminf(ml.x, 0.0f) + (1.0f - m2.x) * fminf(-ml.x, 0.0f)
         - __logf(1.0f + __expf(-fabsf(ml.x)))) +
        (m2.y * fminf(ml.y, 0.0f) + (1.0f - m2.y) * fminf(-ml.y, 0.0f)
         - __logf(1.0f + __expf(-fabsf(ml.y))));

    const float dnx = sqrtf(sq(a0.x - b0.x) + sq(a1.x - b1.x) + sq(a2.x - b2.x));
    const float dny = sqrtf(sq(a0.y - b0.y) + sq(a1.y - b1.y) + sq(a2.y - b2.y));
    const bool sx = m2.x > 0.7f, sy = m2.y > 0.7f;

    // -- skin CE: one 18-channel batch (36 VGPRs of loads in flight) --
    float2 x[18];
#pragma unroll
    for (int k = 0; k < 18; ++k) x[k] = ob[(100 + k) * C2];
    const float2 labf = tb[100 * C2];
    float mxx = x[0].x, mxy = x[0].y;
#pragma unroll
    for (int k = 1; k < 18; ++k) { mxx = fmaxf(mxx, x[k].x); mxy = fmaxf(mxy, x[k].y); }
    float sex = 0.0f, sey = 0.0f;
#pragma unroll
    for (int k = 0; k < 18; ++k) { sex += __expf(x[k].x - mxx); sey += __expf(x[k].y - mxy); }
    int labx = (int)labf.x; labx = labx < 0 ? 0 : (labx > 17 ? 17 : labx);
    int laby = (int)labf.y; laby = laby < 0 ? 0 : (laby > 17 ? 17 : laby);
    float xlx = x[0].x, xly = x[0].y;
#pragma unroll
    for (int k = 1; k < 18; ++k) { xlx = (labx == k) ? x[k].x : xlx;
                                   xly = (laby == k) ? x[k].y : xly; }
    const float skin = (mxx + __logf(sex) - xlx) + (mxy + __logf(sey) - xly);

    // -- joint maps: 12 float2 loads per j, unroll 2 -> 24-load batches --
    float dslx = 0.0f, dsly = 0.0f, dsrx = 0.0f, dsry = 0.0f;
#pragma unroll 2
    for (int j = 0; j < BN; ++j) {
        const int cl = (4 + 3 * j) * C2, cr = (52 + 3 * j) * C2;
        const float2 o0 = ob[cl], o1 = ob[cl + C2], o2 = ob[cl + 2 * C2];
        const float2 t0 = tb[cl], t1 = tb[cl + C2], t2 = tb[cl + 2 * C2];
        const float2 p0 = ob[cr], p1 = ob[cr + C2], p2 = ob[cr + 2 * C2];
        const float2 q0 = tb[cr], q1 = tb[cr + C2], q2 = tb[cr + 2 * C2];
        dslx += sq(fsig(o0.x) - fsig(t0.x)) + sq(fsig(o1.x) - fsig(t1.x))
              + sq(fsig(o2.x) - fsig(t2.x));
        dsly += sq(fsig(o0.y) - fsig(t0.y)) + sq(fsig(o1.y) - fsig(t1.y))
              + sq(fsig(o2.y) - fsig(t2.y));
        dsrx += sq(fsig(p0.x) - fsig(q0.x)) + sq(fsig(p1.x) - fsig(q1.x))
              + sq(fsig(p2.x) - fsig(q2.x));
        dsry += sq(fsig(p0.y) - fsig(q0.y)) + sq(fsig(p1.y) - fsig(q1.y))
              + sq(fsig(p2.y) - fsig(q2.y));
    }
    const float dnlx = sqrtf(dslx), dnly = sqrtf(dsly);
    const float dnrx = sqrtf(dsrx), dnry = sqrtf(dsry);

    // -- 11 wave reductions, both pixels pre-summed --
    float v[11];
    v[0]  = bce;
    v[1]  = skin;
    v[2]  = (sx ? dnx : 0.0f) + (sy ? dny : 0.0f);
    v[3]  = ((sx && dnx != 0.0f) ? 1.0f : 0.0f) + ((sy && dny != 0.0f) ? 1.0f : 0.0f);
    v[4]  = dnx + dny;
    v[5]  = (sx ? dnlx : 0.0f) + (sy ? dnly : 0.0f);
    v[6]  = ((sx && dnlx != 0.0f) ? 1.0f : 0.0f) + ((sy && dnly != 0.0f) ? 1.0f : 0.0f);
    v[7]  = dnlx + dnly;
    v[8]  = (sx ? dnrx : 0.0f) + (sy ? dnry : 0.0f);
    v[9]  = ((sx && dnrx != 0.0f) ? 1.0f : 0.0f) + ((sy && dnry != 0.0f) ? 1.0f : 0.0f);
    v[10] = dnrx + dnry;

#pragma unroll
    for (int off = 32; off; off >>= 1) {
#pragma unroll
        for (int i = 0; i < 11; ++i) v[i] += __shfl_xor(v[i], off, 64);
    }

    __shared__ float red[11][4];
    if (lane == 0) {
#pragma unroll
        for (int i = 0; i < 11; ++i) red[i][wv] = v[i];
    }
    __syncthreads();
    if (threadIdx.x < 11) {
        float s = red[threadIdx.x][0] + red[threadIdx.x][1] +
                  red[threadIdx.x][2] + red[threadIdx.x][3];
        int g = (threadIdx.x < 2) ? threadIdx.x : (2 + b * 9 + (threadIdx.x - 2));
        atomicAdd(&ws[g], s);
    }
}

// ---- Kernel B: per-joint sums, 4 px/thread (float4), 8 loads, no loop ----
__global__ __launch_bounds__(256) void mvpm_joint4(const float* __restrict__ outp,
                                                   const float* __restrict__ tarp,
                                                   float* __restrict__ ws) {
    const int bj = blockIdx.y;            // b*16 + j
    const int b = bj >> 4;
    const int j = bj & 15;
    const int C4 = HW / 4;                // channel stride (float4)
    const int idx = blockIdx.x * 256 + threadIdx.x;     // float4 index
    const float4* ob = (const float4*)(outp + (size_t)b * 134 * HW);
    const int lane = threadIdx.x & 63;
    const int wv = threadIdx.x >> 6;

    // 8 independent float4 loads (2 KB/wave in flight)
    const float4 m  = ((const float4*)(tarp + (size_t)b * 101 * HW))[3 * C4 + idx];
    const float4 s  = ob[(118 + j) * C4 + idx];
    const float4 l0 = ob[(4 + 3 * j) * C4 + idx];
    const float4 l1 = ob[(5 + 3 * j) * C4 + idx];
    const float4 l2 = ob[(6 + 3 * j) * C4 + idx];
    const float4 r0 = ob[(52 + 3 * j) * C4 + idx];
    const float4 r1 = ob[(53 + 3 * j) * C4 + idx];
    const float4 r2 = ob[(54 + 3 * j) * C4 + idx];

    float wx = fsig(s.x) * m.x, wy = fsig(s.y) * m.y,
          wz = fsig(s.z) * m.z, ww = fsig(s.w) * m.w;
    float v[7];
    v[0] = wx + wy + wz + ww;                            // S
    wx *= m.x; wy *= m.y; wz *= m.z; ww *= m.w;          // sig(score)*m^2
    v[1] = fsig(l0.x) * wx + fsig(l0.y) * wy + fsig(l0.z) * wz + fsig(l0.w) * ww;
    v[2] = fsig(l1.x) * wx + fsig(l1.y) * wy + fsig(l1.z) * wz + fsig(l1.w) * ww;
    v[3] = fsig(l2.x) * wx + fsig(l2.y) * wy + fsig(l2.z) * wz + fsig(l2.w) * ww;
    v[4] = fsig(r0.x) * wx + fsig(r0.y) * wy + fsig(r0.z) * wz + fsig(r0.w) * ww;
    v[5] = fsig(r1.x) * wx + fsig(r1.y) * wy + fsig(r1.z) * wz + fsig(r1.w) * ww;
    v[6] = fsig(r2.x) * wx + fsig(r2.y) * wy + fsig(r2.z) * wz + fsig(r2.w) * ww;

#pragma unroll
    for (int off = 32; off; off >>= 1) {
#pragma unroll
        for (int i = 0; i < 7; ++i) v[i] += __shfl_xor(v[i], off, 64);
    }

    __shared__ float red[7][4];
    if (lane == 0) {
#pragma unroll
        for (int i = 0; i < 7; ++i) red[i][wv] = v[i];
    }
    __syncthreads();
    if (threadIdx.x < 7) {
        float sum = red[threadIdx.x][0] + red[threadIdx.x][1] +
                    red[threadIdx.x][2] + red[threadIdx.x][3];
        atomicAdd(&ws[38 + bj * 7 + threadIdx.x], sum);
    }
}

// ---- finalize ------------------------------------------------------------
__global__ __launch_bounds__(64) void mvpm_fin(const float* __restrict__ ws,
                                               const float* __restrict__ tp,
                                               float* __restrict__ o) {
    const int t = threadIdx.x;      // (b, j)
    const int base = 38 + t * 7;

    float S = ws[base] + 1e-5f;
    float ln = 0.0f, rn = 0.0f;
#pragma unroll
    for (int c = 0; c < 3; ++c) {
        float pl = ws[base + 1 + c] / S;
        float tl = 1.0f / (1.0f + expf(-tp[t * 6 + c]));
        ln += (pl - tl) * (pl - tl);
        float pr = ws[base + 4 + c] / S;
        float tr = 1.0f / (1.0f + expf(-tp[t * 6 + 3 + c]));
        rn += (pr - tr) * (pr - tr);
    }
    ln = sqrtf(ln);
    rn = sqrtf(rn);
    float lsum = wred(ln);
    float rsum = wred(rn);

    if (t == 0) {
        float nocs = 0.0f, locm = 0.0f, rotm = 0.0f;
        for (int bb = 0; bb < 4; ++bb) {
            int ba = 2 + bb * 9;
            nocs += (ws[ba + 1] > 0.5f) ? ws[ba + 0] / ws[ba + 1] : ws[ba + 2] * (1.0f / HW);
            locm += (ws[ba + 4] > 0.5f) ? ws[ba + 3] / ws[ba + 4] : ws[ba + 5] * (1.0f / HW);
            rotm += (ws[ba + 7] > 0.5f) ? ws[ba + 6] / ws[ba + 7] : ws[ba + 8] * (1.0f / HW);
        }
        o[0] = nocs * 0.25f;                  // nocs_loss
        o[1] = -ws[0] / (4.0f * HW);          // mask_loss
        o[2] = lsum * (1.0f / 64.0f);         // loc_loss
        o[3] = locm * 0.25f;                  // loc_map_loss
        o[4] = rsum * (1.0f / 64.0f);         // rot_loss
        o[5] = rotm * 0.25f;                  // rot_map_loss
        o[6] = ws[1] / (4.0f * HW);           // skin_loss
    }
}

extern "C" void kernel_launch(void* const* d_in, const int* in_sizes, int n_in,
                              void* d_out, int out_size, void* d_ws, size_t ws_size,
                              hipStream_t stream) {
    const float* outp = (const float*)d_in[0];   // (4,134,256,256)
    const float* tarp = (const float*)d_in[1];   // (4,101,256,256)
    const float* tpos = (const float*)d_in[2];   // (4,16,6)
    float* o  = (float*)d_out;                   // 7 floats
    float* ws = (float*)d_ws;

    hipMemsetAsync(d_ws, 0, 486 * sizeof(float), stream);
    dim3 gA(HW / 512, 4);                        // 512 blocks, 2 px/thread
    mvpm_pix2<<<gA, 256, 0, stream>>>(outp, tarp, ws);
    dim3 gB(HW / 1024, 64);                      // 64 chunks x (b,j) = 4096 blocks
    mvpm_joint4<<<gB, 256, 0, stream>>>(outp, tarp, ws);
    mvpm_fin<<<1, 64, 0, stream>>>(ws, tpos, o);
}